// Round 5
// baseline (284.411 us; speedup 1.0000x reference)
//
#include <hip/hip_runtime.h>

typedef _Float16 half8  __attribute__((ext_vector_type(8)));
typedef _Float16 half4  __attribute__((ext_vector_type(4)));
typedef float    float4v __attribute__((ext_vector_type(4)));

#define N_ROWS  65536   // 64*32*32
#define N_CODES 1024
#define DIM     256
#define CG          16          // code groups
#define CODES_PER_CG 64
#define RB          128         // row blocks
#define ROWS_PER_RB 512

// ---- prep_e (r3/r4-verified): one wave per code. ||e||^2 + f16 hi/lo split in
// MFMA B-frag order: frag block b = nt*8+ks holds 1024 halves [hi 512][lo 512],
// chunk p = quad*16+l15 -> code = nt*16+l15, k = ks*32 + quad*8 + j.
__global__ __launch_bounds__(64)
void vq_prep(const float* __restrict__ emb, float* __restrict__ e_norm,
             _Float16* __restrict__ e_frag) {
    const int c = blockIdx.x, lane = threadIdx.x;
    const int l15 = c & 15, nt = c >> 4;
    float4v v = ((const float4v*)(emb + (size_t)c * DIM))[lane];
    half4 h, l;
    float ss = 0.f;
    #pragma unroll
    for (int j = 0; j < 4; ++j) {
        float x = v[j];
        ss += x * x;
        _Float16 hh = (_Float16)x;
        h[j] = hh;
        l[j] = (_Float16)(x - (float)hh);
    }
    const int ks = lane >> 3, q = (lane >> 1) & 3, jb = (lane & 1) * 4;
    _Float16* p = e_frag + ((size_t)(nt * 8 + ks)) * 1024 + (q * 16 + l15) * 8 + jb;
    *(half4*)p = h;
    *(half4*)(p + 512) = l;
    #pragma unroll
    for (int m = 32; m >= 1; m >>= 1) ss += __shfl_xor(ss, m, 64);
    if (lane == 0) e_norm[c] = ss;
}

// ---- prep_z: one wave per 16-row m-tile. z -> f16 hi/lo in MFMA A-frag order:
// frag g = mtile*8+ks holds [hi 512][lo 512]; lane(l15,quad): row=mtile*16+l15,
// k = ks*32+quad*8+j. Writes fully coalesced (lane*16 B).
__global__ __launch_bounds__(64)
void vq_prep_z(const float* __restrict__ z, _Float16* __restrict__ z_frag) {
    const int mt = blockIdx.x;                      // 0..4095
    const int lane = threadIdx.x, quad = lane >> 4, l15 = lane & 15;
    const float* rowp = z + (size_t)(mt * 16 + l15) * DIM;
    #pragma unroll
    for (int ks = 0; ks < 8; ++ks) {
        const float* p = rowp + ks * 32 + quad * 8;
        float4v a0 = *(const float4v*)p;
        float4v a1 = *(const float4v*)(p + 4);
        half8 h, l;
        #pragma unroll
        for (int j = 0; j < 4; ++j) {
            float x = a0[j]; _Float16 hx = (_Float16)x;
            h[j] = hx; l[j] = (_Float16)(x - (float)hx);
            float y = a1[j]; _Float16 hy = (_Float16)y;
            h[4 + j] = hy; l[4 + j] = (_Float16)(y - (float)hy);
        }
        _Float16* dst = z_frag + ((size_t)mt * 8 + ks) * 1024 + lane * 8;
        *(half8*)dst = h;
        *(half8*)(dst + 512) = l;
    }
}

// ---- main (pre-split path): 512 thr (8 waves), block = 512 rows x 64 codes.
// B-slice 64 KB in LDS (staged once, ONE barrier). A: pure half8 global loads
// (L2-hot via XCD grouping). Wave = 64 rows x 64 codes, acc = 64 AGPR.
// __launch_bounds__(512,4): target 128 unified regs -> 4 waves/SIMD, 2 blocks/CU.
__global__ __launch_bounds__(512, 4)
void vq_main_pre(const _Float16* __restrict__ z_frag,
                 const _Float16* __restrict__ e_frag,
                 const float* __restrict__ e_norm,
                 float2* __restrict__ partial) {
    __shared__ _Float16 sB[32768];        // 64 KB
    __shared__ float s_nrm[CODES_PER_CG];

    const int t = threadIdx.x;
    const int w = t >> 6, lane = t & 63, quad = lane >> 4, l15 = lane & 15;
    const int rb = blockIdx.x, cg = blockIdx.y;   // cg-mates: id stride 128 -> same XCD

    {   // stage B slice: 64 KB contiguous, coalesced, conflict-free
        const _Float16* src = e_frag + (size_t)cg * 32768;
        #pragma unroll
        for (int i = 0; i < 8; ++i)
            *(half8*)(sB + i * 4096 + t * 8) = *(const half8*)(src + i * 4096 + t * 8);
        if (t < CODES_PER_CG) s_nrm[t] = e_norm[cg * CODES_PER_CG + t];
    }
    __syncthreads();   // the only barrier

    const int rt0 = rb * 32 + w * 4;
    const int rowbase = rb * ROWS_PER_RB + w * 64;

    float4v acc[4][4] = {};

    for (int ks = 0; ks < 8; ++ks) {
        half8 ah[4], al[4];
        #pragma unroll
        for (int mt = 0; mt < 4; ++mt) {
            const _Float16* ap = z_frag + ((size_t)(rt0 + mt) * 8 + ks) * 1024 + lane * 8;
            ah[mt] = *(const half8*)ap;
            al[mt] = *(const half8*)(ap + 512);
        }
        #pragma unroll
        for (int ntl = 0; ntl < 4; ++ntl) {
            const _Float16* bp = sB + (ntl * 8 + ks) * 1024 + lane * 8;
            half8 bh = *(const half8*)bp;
            half8 bl = *(const half8*)(bp + 512);
            // per-acc order hh,hl,lh (bit-identical to r2-r4); mt-interleave
            // gives chain distance 4 for MFMA latency hiding
            #pragma unroll
            for (int mt = 0; mt < 4; ++mt)
                acc[mt][ntl] = __builtin_amdgcn_mfma_f32_16x16x32_f16(ah[mt], bh, acc[mt][ntl], 0, 0, 0);
            #pragma unroll
            for (int mt = 0; mt < 4; ++mt)
                acc[mt][ntl] = __builtin_amdgcn_mfma_f32_16x16x32_f16(ah[mt], bl, acc[mt][ntl], 0, 0, 0);
            #pragma unroll
            for (int mt = 0; mt < 4; ++mt)
                acc[mt][ntl] = __builtin_amdgcn_mfma_f32_16x16x32_f16(al[mt], bh, acc[mt][ntl], 0, 0, 0);
        }
    }

    // ---- epilogue: score = ||e||^2 - 2*dot; argmin. C/D: col=l15, row=quad*4+r
    float nrm[4]; int cbase[4];
    #pragma unroll
    for (int ntl = 0; ntl < 4; ++ntl) {
        cbase[ntl] = cg * CODES_PER_CG + ntl * 16 + l15;
        nrm[ntl]   = s_nrm[ntl * 16 + l15];
    }
    #pragma unroll
    for (int mt = 0; mt < 4; ++mt) {
        #pragma unroll
        for (int r = 0; r < 4; ++r) {
            float bs = 0.f; int bi = 0;
            #pragma unroll
            for (int ntl = 0; ntl < 4; ++ntl) {
                float s = nrm[ntl] - 2.0f * acc[mt][ntl][r];
                if (ntl == 0 || s < bs) { bs = s; bi = cbase[ntl]; }  // ascending: strict < = lowest idx
            }
            #pragma unroll
            for (int m = 1; m < 16; m <<= 1) {
                float s2 = __shfl_xor(bs, m, 64);
                int   i2 = __shfl_xor(bi, m, 64);
                if (s2 < bs || (s2 == bs && i2 < bi)) { bs = s2; bi = i2; }
            }
            if (l15 == 0) {
                const int row = rowbase + mt * 16 + quad * 4 + r;
                float2 pr; pr.x = bs; pr.y = (float)bi;
                partial[(size_t)row * CG + cg] = pr;
            }
        }
    }
}

// ---- main (inline-convert fallback, only if ws is tiny): r4-style A path
__global__ __launch_bounds__(512, 2)
void vq_main_inl(const float* __restrict__ z,
                 const _Float16* __restrict__ e_frag,
                 const float* __restrict__ e_norm,
                 float2* __restrict__ partial) {
    __shared__ _Float16 sB[32768];
    __shared__ float s_nrm[CODES_PER_CG];

    const int t = threadIdx.x;
    const int w = t >> 6, lane = t & 63, quad = lane >> 4, l15 = lane & 15;
    const int rb = blockIdx.x, cg = blockIdx.y;

    {
        const _Float16* src = e_frag + (size_t)cg * 32768;
        #pragma unroll
        for (int i = 0; i < 8; ++i)
            *(half8*)(sB + i * 4096 + t * 8) = *(const half8*)(src + i * 4096 + t * 8);
        if (t < CODES_PER_CG) s_nrm[t] = e_norm[cg * CODES_PER_CG + t];
    }
    __syncthreads();

    const int rowbase = rb * ROWS_PER_RB + w * 64;
    float4v acc[4][4] = {};

    for (int ks = 0; ks < 8; ++ks) {
        half8 ah[4], al[4];
        #pragma unroll
        for (int mt = 0; mt < 4; ++mt) {
            const float* ap = z + (size_t)(rowbase + mt * 16 + l15) * DIM + ks * 32 + quad * 8;
            float4v a0 = *(const float4v*)ap;
            float4v a1 = *(const float4v*)(ap + 4);
            #pragma unroll
            for (int j = 0; j < 4; ++j) {
                float x = a0[j]; _Float16 hx = (_Float16)x;
                ah[mt][j] = hx; al[mt][j] = (_Float16)(x - (float)hx);
                float y = a1[j]; _Float16 hy = (_Float16)y;
                ah[mt][4 + j] = hy; al[mt][4 + j] = (_Float16)(y - (float)hy);
            }
        }
        #pragma unroll
        for (int ntl = 0; ntl < 4; ++ntl) {
            const _Float16* bp = sB + (ntl * 8 + ks) * 1024 + lane * 8;
            half8 bh = *(const half8*)bp;
            half8 bl = *(const half8*)(bp + 512);
            #pragma unroll
            for (int mt = 0; mt < 4; ++mt)
                acc[mt][ntl] = __builtin_amdgcn_mfma_f32_16x16x32_f16(ah[mt], bh, acc[mt][ntl], 0, 0, 0);
            #pragma unroll
            for (int mt = 0; mt < 4; ++mt)
                acc[mt][ntl] = __builtin_amdgcn_mfma_f32_16x16x32_f16(ah[mt], bl, acc[mt][ntl], 0, 0, 0);
            #pragma unroll
            for (int mt = 0; mt < 4; ++mt)
                acc[mt][ntl] = __builtin_amdgcn_mfma_f32_16x16x32_f16(al[mt], bh, acc[mt][ntl], 0, 0, 0);
        }
    }

    float nrm[4]; int cbase[4];
    #pragma unroll
    for (int ntl = 0; ntl < 4; ++ntl) {
        cbase[ntl] = cg * CODES_PER_CG + ntl * 16 + l15;
        nrm[ntl]   = s_nrm[ntl * 16 + l15];
    }
    #pragma unroll
    for (int mt = 0; mt < 4; ++mt) {
        #pragma unroll
        for (int r = 0; r < 4; ++r) {
            float bs = 0.f; int bi = 0;
            #pragma unroll
            for (int ntl = 0; ntl < 4; ++ntl) {
                float s = nrm[ntl] - 2.0f * acc[mt][ntl][r];
                if (ntl == 0 || s < bs) { bs = s; bi = cbase[ntl]; }
            }
            #pragma unroll
            for (int m = 1; m < 16; m <<= 1) {
                float s2 = __shfl_xor(bs, m, 64);
                int   i2 = __shfl_xor(bi, m, 64);
                if (s2 < bs || (s2 == bs && i2 < bi)) { bs = s2; bi = i2; }
            }
            if (l15 == 0) {
                const int row = rowbase + mt * 16 + quad * 4 + r;
                float2 pr; pr.x = bs; pr.y = (float)bi;
                partial[(size_t)row * CG + cg] = pr;
            }
        }
    }
}

// ---- final argmin over 16 cg partials per row ----
__global__ __launch_bounds__(256)
void vq_reduce(const float2* __restrict__ partial, float* __restrict__ idxf) {
    const int r = blockIdx.x * 256 + threadIdx.x;
    const float2* p = partial + (size_t)r * CG;
    float bsv = p[0].x, biv = p[0].y;
    #pragma unroll
    for (int s = 1; s < CG; ++s) {
        float2 v = p[s];
        if (v.x < bsv || (v.x == bsv && v.y < biv)) { bsv = v.x; biv = v.y; }
    }
    idxf[r] = biv;
}

// ---- one wave per row: lane i copies float4 #i of the winning code row ----
__global__ __launch_bounds__(256)
void vq_gather(const float* __restrict__ emb,
               const float* __restrict__ idxf,
               float* __restrict__ zq) {
    const int tid  = blockIdx.x * 256 + threadIdx.x;
    const int r    = tid >> 6;
    const int lane = tid & 63;
    const int idx  = (int)idxf[r];
    const float4* ep = (const float4*)(emb + (size_t)idx * DIM);
    ((float4*)(zq + (size_t)r * DIM))[lane] = ep[lane];
}

extern "C" void kernel_launch(void* const* d_in, const int* in_sizes, int n_in,
                              void* d_out, int out_size, void* d_ws, size_t ws_size,
                              hipStream_t stream) {
    const float* z   = (const float*)d_in[0];   // (64,32,32,256) fp32
    const float* emb = (const float*)d_in[1];   // (1024,256) fp32

    float* zq   = (float*)d_out;                        // output 0: 16,777,216 f
    float* idxf = zq + (size_t)N_ROWS * DIM;            // output 1: 65,536 f

    const size_t zfrag_b = (size_t)N_ROWS * DIM * 2 * sizeof(_Float16);       // 64 MiB
    const size_t efrag_b = (size_t)N_CODES * DIM * 2 * sizeof(_Float16);      // 1 MiB
    const size_t part_b  = (size_t)N_ROWS * CG * sizeof(float2);              // 8 MiB
    const size_t small_b = 4096 + efrag_b + part_b;

    char* small;
    _Float16* z_frag = nullptr;
    int pre;
    if (ws_size >= zfrag_b + small_b) {          // path A: everything in ws
        z_frag = (_Float16*)d_ws;
        small  = (char*)d_ws + zfrag_b;
        pre = 1;
    } else if (ws_size >= small_b) {             // path B: z_frag in zq area (64 MiB exact;
        z_frag = (_Float16*)zq;                  // gather overwrites it last)
        small  = (char*)d_ws;
        pre = 1;
    } else {                                     // path C: no room for z_frag -> inline convert
        small = (char*)zq;
        pre = 0;
    }
    float*    e_norm  = (float*)small;
    _Float16* e_frag  = (_Float16*)(small + 4096);
    float2*   partial = (float2*)(small + 4096 + efrag_b);

    vq_prep<<<N_CODES, 64, 0, stream>>>(emb, e_norm, e_frag);
    if (pre) {
        vq_prep_z<<<N_ROWS / 16, 64, 0, stream>>>(z, z_frag);
        vq_main_pre<<<dim3(RB, CG), 512, 0, stream>>>(z_frag, e_frag, e_norm, partial);
    } else {
        vq_main_inl<<<dim3(RB, CG), 512, 0, stream>>>(z, e_frag, e_norm, partial);
    }
    vq_reduce<<<N_ROWS / 256, 256, 0, stream>>>(partial, idxf);
    vq_gather<<<(N_ROWS * 64) / 256, 256, 0, stream>>>(emb, idxf, zq);
}